// Round 2
// baseline (375.056 us; speedup 1.0000x reference)
//
#include <hip/hip_runtime.h>

// Problem constants (fixed by the reference)
#define B_ 512
#define T_ 256
#define C_ 384
#define H_ 64
#define WT_STRIDE (H_ * C_)   // 24576 elements per matrix in WT scratch

typedef __bf16 bf16;
typedef bf16  bf16x8 __attribute__((ext_vector_type(8)));
typedef float f32x4  __attribute__((ext_vector_type(4)));

// ---------------- prep: W (fp32 [C][H]) -> WT (bf16 [mat][h][k]) ----------------
__global__ void prep_wt(const float* __restrict__ Wq,
                        const float* __restrict__ Wk,
                        const float* __restrict__ Wv,
                        bf16* __restrict__ wt)
{
    int idx = blockIdx.x * 256 + threadIdx.x;
    if (idx >= 3 * WT_STRIDE) return;
    int mat = idx / WT_STRIDE;
    int r   = idx % WT_STRIDE;
    int h   = r / C_;
    int k   = r % C_;
    const float* W = (mat == 0) ? Wq : (mat == 1) ? Wk : Wv;
    wt[idx] = (bf16)W[k * H_ + h];
}

__device__ __forceinline__ bf16x8 cvt8(float4 a, float4 b)
{
    bf16x8 r;
    r[0] = (bf16)a.x; r[1] = (bf16)a.y; r[2] = (bf16)a.z; r[3] = (bf16)a.w;
    r[4] = (bf16)b.x; r[5] = (bf16)b.y; r[6] = (bf16)b.z; r[7] = (bf16)b.w;
    return r;
}

// B-fragment: 8 consecutive k at fixed output column `col`.
__device__ __forceinline__ bf16x8 load_bfrag(const bf16* __restrict__ wt,
                                             const float* __restrict__ W,
                                             int use_wt, int mat, int col, int k)
{
    if (use_wt) {
        return *reinterpret_cast<const bf16x8*>(wt + mat * WT_STRIDE + col * C_ + k);
    } else {
        bf16x8 r;
        const float* wp = W + k * H_ + col;
        #pragma unroll
        for (int j = 0; j < 8; ++j) r[j] = (bf16)wp[j * H_];
        return r;
    }
}

// XOR swizzle: permute 8-elem (16B) chunks within a row by low row bits.
#define SWZ(row, col) ((col) ^ (((row) & 7) << 3))

__global__ __launch_bounds__(512, 4)
void head_fused2(const float* __restrict__ x,
                 const float* __restrict__ Wq,
                 const float* __restrict__ Wk,
                 const float* __restrict__ Wv,
                 const bf16* __restrict__ wt,
                 float* __restrict__ out,
                 int use_wt)
{
    // 32768 + 32768 + 16384 = 81920 B  (2 blocks/CU at 160 KiB)
    __shared__ bf16 k_s[T_ * 64];       // [t=256][h=64]  swizzled
    __shared__ bf16 vT_s[H_ * 256];     // [h=64][t=256]  swizzled
    __shared__ bf16 p_s[8 * 16 * 64];   // per-wave bounce (q then P), swizzled

    const int tid  = threadIdx.x;
    const int wave = tid >> 6;
    const int lane = tid & 63;
    const int lr   = lane & 15;
    const int lg   = lane >> 4;

    const int b = blockIdx.x;
    const float* xb = x + (size_t)b * T_ * C_;

    // ---------------- Phase 1: k and v projections ----------------
    // wave w owns row tiles {w, 15-w} (also its phase-2 q tiles: 17 kt-units each)
    #pragma unroll 1
    for (int p = 0; p < 2; ++p) {
        const int mt = p ? (15 - wave) : wave;
        f32x4 acc[2][4];
        #pragma unroll
        for (int a = 0; a < 2; ++a)
            #pragma unroll
            for (int nw = 0; nw < 4; ++nw)
                acc[a][nw] = (f32x4){0.f, 0.f, 0.f, 0.f};

        const float* xrow = xb + (mt * 16 + lr) * C_;
        #pragma unroll
        for (int ks = 0; ks < 12; ++ks) {
            const float* xp = xrow + ks * 32 + lg * 8;
            float4 a0 = *reinterpret_cast<const float4*>(xp);
            float4 a1 = *reinterpret_cast<const float4*>(xp + 4);
            bf16x8 af = cvt8(a0, a1);
            #pragma unroll
            for (int nw = 0; nw < 4; ++nw) {
                bf16x8 bk = load_bfrag(wt, Wk, use_wt, 1, nw * 16 + lr, ks * 32 + lg * 8);
                acc[0][nw] = __builtin_amdgcn_mfma_f32_16x16x32_bf16(af, bk, acc[0][nw], 0, 0, 0);
                bf16x8 bv = load_bfrag(wt, Wv, use_wt, 2, nw * 16 + lr, ks * 32 + lg * 8);
                acc[1][nw] = __builtin_amdgcn_mfma_f32_16x16x32_bf16(af, bv, acc[1][nw], 0, 0, 0);
            }
        }
        // D layout: row = lg*4+r (within tile), col = lr (within n-block)
        #pragma unroll
        for (int nw = 0; nw < 4; ++nw) {
            #pragma unroll
            for (int r = 0; r < 4; ++r) {
                int row = mt * 16 + lg * 4 + r;   // t
                int col = nw * 16 + lr;           // h
                k_s[row * 64 + SWZ(row, col)]   = (bf16)acc[0][nw][r];
                vT_s[col * 256 + SWZ(col, row)] = (bf16)acc[1][nw][r];
            }
        }
    }
    __syncthreads();

    // ---------------- Phase 2: q projection + causal attention ----------------
    const float scale = 0.051031036307982884f;   // 384^-0.5 (C, not H)
    bf16* pw = &p_s[wave * 16 * 64];

    #pragma unroll 1
    for (int p = 0; p < 2; ++p) {
        const int mt  = p ? (15 - wave) : wave;
        const int nkt = mt + 1;

        // q = x @ Wq for this 16-row tile (just-in-time; x re-read hits L2/L3)
        f32x4 qa[4];
        #pragma unroll
        for (int nw = 0; nw < 4; ++nw) qa[nw] = (f32x4){0.f, 0.f, 0.f, 0.f};
        const float* xrow = xb + (mt * 16 + lr) * C_;
        #pragma unroll
        for (int ks = 0; ks < 12; ++ks) {
            const float* xp = xrow + ks * 32 + lg * 8;
            float4 a0 = *reinterpret_cast<const float4*>(xp);
            float4 a1 = *reinterpret_cast<const float4*>(xp + 4);
            bf16x8 af = cvt8(a0, a1);
            #pragma unroll
            for (int nw = 0; nw < 4; ++nw) {
                bf16x8 bq = load_bfrag(wt, Wq, use_wt, 0, nw * 16 + lr, ks * 32 + lg * 8);
                qa[nw] = __builtin_amdgcn_mfma_f32_16x16x32_bf16(af, bq, qa[nw], 0, 0, 0);
            }
        }
        // D-layout -> A-layout transpose via per-wave bounce
        #pragma unroll
        for (int nw = 0; nw < 4; ++nw) {
            #pragma unroll
            for (int r = 0; r < 4; ++r) {
                int row = lg * 4 + r;
                pw[row * 64 + SWZ(row, nw * 16 + lr)] = (bf16)qa[nw][r];
            }
        }
        asm volatile("s_waitcnt lgkmcnt(0)" ::: "memory");
        __builtin_amdgcn_sched_barrier(0);
        bf16x8 qf0 = *reinterpret_cast<const bf16x8*>(&pw[lr * 64 + SWZ(lr, lg * 8)]);
        bf16x8 qf1 = *reinterpret_cast<const bf16x8*>(&pw[lr * 64 + SWZ(lr, 32 + lg * 8)]);

        // scores: full 16x256 strip in registers (static indices)
        float s[16][4];
        #pragma unroll
        for (int kt = 0; kt < 16; ++kt) {
            if (kt < nkt) {   // wave-uniform
                bf16x8 kf0 = *reinterpret_cast<const bf16x8*>(
                    &k_s[(kt * 16 + lr) * 64 + SWZ(lr, lg * 8)]);
                bf16x8 kf1 = *reinterpret_cast<const bf16x8*>(
                    &k_s[(kt * 16 + lr) * 64 + SWZ(lr, 32 + lg * 8)]);
                f32x4 sc = (f32x4){0.f, 0.f, 0.f, 0.f};
                sc = __builtin_amdgcn_mfma_f32_16x16x32_bf16(qf0, kf0, sc, 0, 0, 0);
                sc = __builtin_amdgcn_mfma_f32_16x16x32_bf16(qf1, kf1, sc, 0, 0, 0);
                #pragma unroll
                for (int r = 0; r < 4; ++r) {
                    float v = sc[r] * scale;
                    if (kt == mt && lr > lg * 4 + r) v = -1e30f;   // causal diag
                    s[kt][r] = v;
                }
            } else {
                #pragma unroll
                for (int r = 0; r < 4; ++r) s[kt][r] = -1e30f;
            }
        }

        // softmax: row (lg*4+r) lives across the 16 lanes of this group
        float inv[4];
        #pragma unroll
        for (int r = 0; r < 4; ++r) {
            float m = s[0][r];
            #pragma unroll
            for (int kt = 1; kt < 16; ++kt) m = fmaxf(m, s[kt][r]);
            m = fmaxf(m, __shfl_xor(m, 1));
            m = fmaxf(m, __shfl_xor(m, 2));
            m = fmaxf(m, __shfl_xor(m, 4));
            m = fmaxf(m, __shfl_xor(m, 8));
            float t = 0.f;
            #pragma unroll
            for (int kt = 0; kt < 16; ++kt) {
                float e = __expf(s[kt][r] - m);
                s[kt][r] = e;
                t += e;
            }
            t += __shfl_xor(t, 1);
            t += __shfl_xor(t, 2);
            t += __shfl_xor(t, 4);
            t += __shfl_xor(t, 8);
            inv[r] = 1.0f / t;
        }

        // PV: P through the (now free) bounce to get A-fragment layout
        f32x4 oacc[4];
        #pragma unroll
        for (int n = 0; n < 4; ++n) oacc[n] = (f32x4){0.f, 0.f, 0.f, 0.f};

        const int nkk = (nkt + 1) >> 1;
        #pragma unroll
        for (int kk = 0; kk < 8; ++kk) {
            if (kk < nkk) {   // wave-uniform
                #pragma unroll
                for (int r = 0; r < 4; ++r) {
                    int row = lg * 4 + r;
                    pw[row * 64 + SWZ(row, lr)]      = (bf16)(s[2 * kk][r]     * inv[r]);
                    pw[row * 64 + SWZ(row, 16 + lr)] = (bf16)(s[2 * kk + 1][r] * inv[r]);
                }
                asm volatile("s_waitcnt lgkmcnt(0)" ::: "memory");
                __builtin_amdgcn_sched_barrier(0);
                bf16x8 pf = *reinterpret_cast<const bf16x8*>(&pw[lr * 64 + SWZ(lr, lg * 8)]);
                #pragma unroll
                for (int n = 0; n < 4; ++n) {
                    bf16x8 vf = *reinterpret_cast<const bf16x8*>(
                        &vT_s[(n * 16 + lr) * 256 + SWZ(lr, kk * 32 + lg * 8)]);
                    oacc[n] = __builtin_amdgcn_mfma_f32_16x16x32_bf16(pf, vf, oacc[n], 0, 0, 0);
                }
            }
        }

        float* op = out + ((size_t)b * T_ + mt * 16) * H_;
        #pragma unroll
        for (int n = 0; n < 4; ++n)
            #pragma unroll
            for (int r = 0; r < 4; ++r)
                op[(lg * 4 + r) * H_ + n * 16 + lr] = oacc[n][r];
    }
}

extern "C" void kernel_launch(void* const* d_in, const int* in_sizes, int n_in,
                              void* d_out, int out_size, void* d_ws, size_t ws_size,
                              hipStream_t stream)
{
    (void)in_sizes; (void)n_in; (void)out_size;
    const float* x  = (const float*)d_in[0];
    const float* Wq = (const float*)d_in[1];
    const float* Wk = (const float*)d_in[2];
    const float* Wv = (const float*)d_in[3];
    float* o = (float*)d_out;

    int use_wt = (ws_size >= (size_t)(3 * WT_STRIDE * sizeof(bf16))) ? 1 : 0;
    bf16* wt = (bf16*)d_ws;
    if (use_wt)
        prep_wt<<<dim3((3 * WT_STRIDE + 255) / 256), dim3(256), 0, stream>>>(Wq, Wk, Wv, wt);
    head_fused2<<<dim3(B_), dim3(512), 0, stream>>>(x, Wq, Wk, Wv, wt, o, use_wt);
}

// Round 3
// 216.134 us; speedup vs baseline: 1.7353x; 1.7353x over previous
//
#include <hip/hip_runtime.h>

// Problem constants (fixed by the reference)
#define B_ 512
#define T_ 256
#define C_ 384
#define H_ 64
#define WT_STRIDE (H_ * C_)   // 24576 elements per matrix in WT scratch

typedef __bf16 bf16;
typedef bf16  bf16x8 __attribute__((ext_vector_type(8)));
typedef float f32x4  __attribute__((ext_vector_type(4)));

// ---------------- prep: W (fp32 [C][H]) -> WT (bf16 [mat][h][k]) ----------------
__global__ void prep_wt(const float* __restrict__ Wq,
                        const float* __restrict__ Wk,
                        const float* __restrict__ Wv,
                        bf16* __restrict__ wt)
{
    int idx = blockIdx.x * 256 + threadIdx.x;
    if (idx >= 3 * WT_STRIDE) return;
    int mat = idx / WT_STRIDE;
    int r   = idx % WT_STRIDE;
    int h   = r / C_;
    int k   = r % C_;
    const float* W = (mat == 0) ? Wq : (mat == 1) ? Wk : Wv;
    wt[idx] = (bf16)W[k * H_ + h];
}

__device__ __forceinline__ bf16x8 cvt8(float4 a, float4 b)
{
    bf16x8 r;
    r[0] = (bf16)a.x; r[1] = (bf16)a.y; r[2] = (bf16)a.z; r[3] = (bf16)a.w;
    r[4] = (bf16)b.x; r[5] = (bf16)b.y; r[6] = (bf16)b.z; r[7] = (bf16)b.w;
    return r;
}

template<int USE_WT>
__device__ __forceinline__ bf16x8 load_bfrag(const bf16* __restrict__ wt,
                                             const float* __restrict__ W,
                                             int mat, int col, int k)
{
    if (USE_WT) {
        return *reinterpret_cast<const bf16x8*>(wt + mat * WT_STRIDE + col * C_ + k);
    } else {
        bf16x8 r;
        const float* wp = W + k * H_ + col;
        #pragma unroll
        for (int j = 0; j < 8; ++j) r[j] = (bf16)wp[j * H_];
        return r;
    }
}

// XOR swizzle: permute 8-elem (16B) chunks within a row by low row bits.
#define SWZ(row, col) ((col) ^ (((row) & 7) << 3))

template<int USE_WT>
__global__ __launch_bounds__(512, 2)   // 2 blocks/CU (observed blocks-semantics) -> VGPR cap 128
void head_fused3(const float* __restrict__ x,
                 const float* __restrict__ Wq,
                 const float* __restrict__ Wk,
                 const float* __restrict__ Wv,
                 const bf16* __restrict__ wt,
                 float* __restrict__ out)
{
    // 32768 + 32768 + 16384 = 81920 B -> exactly 2 blocks / 160 KiB CU
    __shared__ bf16 k_s[T_ * 64];       // [t=256][h=64]  swizzled
    __shared__ bf16 vT_s[H_ * 256];     // [h=64][t=256]  swizzled
    __shared__ bf16 p_s[8 * 16 * 64];   // per-wave bounce (q then P), swizzled

    const int tid  = threadIdx.x;
    const int wave = tid >> 6;
    const int lane = tid & 63;
    const int lr   = lane & 15;
    const int lg   = lane >> 4;

    const int b = blockIdx.x;
    const float* xb = x + (size_t)b * T_ * C_;
    bf16* pw = &p_s[wave * 16 * 64];

    bf16x8 qf[2][2];   // q A-fragments for this wave's two q-tiles (kept in regs)

    // ---------------- Phase 1: q,k,v projections (x read ONCE) ----------------
    // wave w owns row tiles {w, 15-w}; q stays in regs, k/vT go to LDS.
    #pragma unroll
    for (int p = 0; p < 2; ++p) {
        const int mt = p ? (15 - wave) : wave;
        f32x4 acc[3][4];   // q, k, v
        #pragma unroll
        for (int a = 0; a < 3; ++a)
            #pragma unroll
            for (int nw = 0; nw < 4; ++nw)
                acc[a][nw] = (f32x4){0.f, 0.f, 0.f, 0.f};

        const float* xrow = xb + (mt * 16 + lr) * C_;
        #pragma unroll
        for (int ks = 0; ks < 12; ++ks) {
            const float* xp = xrow + ks * 32 + lg * 8;
            float4 a0 = *reinterpret_cast<const float4*>(xp);
            float4 a1 = *reinterpret_cast<const float4*>(xp + 4);
            bf16x8 af = cvt8(a0, a1);
            #pragma unroll
            for (int nw = 0; nw < 4; ++nw) {
                bf16x8 bq = load_bfrag<USE_WT>(wt, Wq, 0, nw * 16 + lr, ks * 32 + lg * 8);
                acc[0][nw] = __builtin_amdgcn_mfma_f32_16x16x32_bf16(af, bq, acc[0][nw], 0, 0, 0);
                bf16x8 bk = load_bfrag<USE_WT>(wt, Wk, 1, nw * 16 + lr, ks * 32 + lg * 8);
                acc[1][nw] = __builtin_amdgcn_mfma_f32_16x16x32_bf16(af, bk, acc[1][nw], 0, 0, 0);
                bf16x8 bv = load_bfrag<USE_WT>(wt, Wv, 2, nw * 16 + lr, ks * 32 + lg * 8);
                acc[2][nw] = __builtin_amdgcn_mfma_f32_16x16x32_bf16(af, bv, acc[2][nw], 0, 0, 0);
            }
        }
        // D layout: row = lg*4+r (within tile), col = lr (within n-block)
        #pragma unroll
        for (int nw = 0; nw < 4; ++nw) {
            #pragma unroll
            for (int r = 0; r < 4; ++r) {
                int row = mt * 16 + lg * 4 + r;   // t
                int col = nw * 16 + lr;           // h
                k_s[row * 64 + SWZ(row, col)]   = (bf16)acc[1][nw][r];
                vT_s[col * 256 + SWZ(col, row)] = (bf16)acc[2][nw][r];
            }
        }
        // q: D-layout -> A-fragment layout via per-wave bounce, keep in regs
        #pragma unroll
        for (int nw = 0; nw < 4; ++nw) {
            #pragma unroll
            for (int r = 0; r < 4; ++r) {
                int row = lg * 4 + r;
                pw[row * 64 + SWZ(row, nw * 16 + lr)] = (bf16)acc[0][nw][r];
            }
        }
        asm volatile("s_waitcnt lgkmcnt(0)" ::: "memory");
        __builtin_amdgcn_sched_barrier(0);
        qf[p][0] = *reinterpret_cast<const bf16x8*>(&pw[lr * 64 + SWZ(lr, lg * 8)]);
        qf[p][1] = *reinterpret_cast<const bf16x8*>(&pw[lr * 64 + SWZ(lr, 32 + lg * 8)]);
    }
    __syncthreads();   // k_s / vT_s complete

    // ---------------- Phase 2: causal attention, flash-style two halves ----------------
    const float scale = 0.051031036307982884f;   // 384^-0.5 (C, not H)

    #pragma unroll
    for (int p = 0; p < 2; ++p) {
        const int mt  = p ? (15 - wave) : wave;
        const int nkt = mt + 1;                   // valid key tiles

        float m[4], l[4];
        f32x4 oacc[4];
        #pragma unroll
        for (int r = 0; r < 4; ++r) { m[r] = -1e30f; l[r] = 0.f; }
        #pragma unroll
        for (int n = 0; n < 4; ++n) oacc[n] = (f32x4){0.f, 0.f, 0.f, 0.f};

        #pragma unroll
        for (int h = 0; h < 2; ++h) {
            const int vh = (nkt - h * 8) < 8 ? (nkt - h * 8) : 8;   // valid tiles in half
            if (vh > 0) {   // wave-uniform
                float s[8][4];
                #pragma unroll
                for (int j = 0; j < 8; ++j) {
                    const int kt = h * 8 + j;
                    if (j < vh) {   // wave-uniform
                        bf16x8 kf0 = *reinterpret_cast<const bf16x8*>(
                            &k_s[(kt * 16 + lr) * 64 + SWZ(lr, lg * 8)]);
                        bf16x8 kf1 = *reinterpret_cast<const bf16x8*>(
                            &k_s[(kt * 16 + lr) * 64 + SWZ(lr, 32 + lg * 8)]);
                        f32x4 sc = (f32x4){0.f, 0.f, 0.f, 0.f};
                        sc = __builtin_amdgcn_mfma_f32_16x16x32_bf16(qf[p][0], kf0, sc, 0, 0, 0);
                        sc = __builtin_amdgcn_mfma_f32_16x16x32_bf16(qf[p][1], kf1, sc, 0, 0, 0);
                        #pragma unroll
                        for (int r = 0; r < 4; ++r) {
                            float v = sc[r] * scale;
                            if (kt == mt && lr > lg * 4 + r) v = -1e30f;   // causal diag
                            s[j][r] = v;
                        }
                    } else {
                        #pragma unroll
                        for (int r = 0; r < 4; ++r) s[j][r] = -1e30f;
                    }
                }

                // per-row max of this half (row lg*4+r spans the 16 lanes of the group)
                float f[4];
                #pragma unroll
                for (int r = 0; r < 4; ++r) {
                    float pm = s[0][r];
                    #pragma unroll
                    for (int j = 1; j < 8; ++j) pm = fmaxf(pm, s[j][r]);
                    pm = fmaxf(pm, __shfl_xor(pm, 1));
                    pm = fmaxf(pm, __shfl_xor(pm, 2));
                    pm = fmaxf(pm, __shfl_xor(pm, 4));
                    pm = fmaxf(pm, __shfl_xor(pm, 8));
                    float nm = fmaxf(m[r], pm);
                    f[r] = __expf(m[r] - nm);   // rescale factor (0 on first half)
                    m[r] = nm;
                    l[r] *= f[r];
                }
                #pragma unroll
                for (int n = 0; n < 4; ++n)
                    #pragma unroll
                    for (int r = 0; r < 4; ++r)
                        oacc[n][r] *= f[r];

                // exp + row sum
                #pragma unroll
                for (int r = 0; r < 4; ++r) {
                    float t = 0.f;
                    #pragma unroll
                    for (int j = 0; j < 8; ++j) {
                        float e = __expf(s[j][r] - m[r]);
                        s[j][r] = e;
                        t += e;
                    }
                    t += __shfl_xor(t, 1);
                    t += __shfl_xor(t, 2);
                    t += __shfl_xor(t, 4);
                    t += __shfl_xor(t, 8);
                    l[r] += t;
                }

                // PV (unnormalized P through the bounce)
                const int nkk = (vh + 1) >> 1;
                #pragma unroll
                for (int kkl = 0; kkl < 4; ++kkl) {
                    if (kkl < nkk) {   // wave-uniform
                        const int kk = h * 4 + kkl;
                        #pragma unroll
                        for (int r = 0; r < 4; ++r) {
                            int row = lg * 4 + r;
                            pw[row * 64 + SWZ(row, lr)]      = (bf16)s[2 * kkl][r];
                            pw[row * 64 + SWZ(row, 16 + lr)] = (bf16)s[2 * kkl + 1][r];
                        }
                        asm volatile("s_waitcnt lgkmcnt(0)" ::: "memory");
                        __builtin_amdgcn_sched_barrier(0);
                        bf16x8 pf = *reinterpret_cast<const bf16x8*>(
                            &pw[lr * 64 + SWZ(lr, lg * 8)]);
                        #pragma unroll
                        for (int n = 0; n < 4; ++n) {
                            bf16x8 vf = *reinterpret_cast<const bf16x8*>(
                                &vT_s[(n * 16 + lr) * 256 + SWZ(lr, kk * 32 + lg * 8)]);
                            oacc[n] = __builtin_amdgcn_mfma_f32_16x16x32_bf16(pf, vf, oacc[n], 0, 0, 0);
                        }
                    }
                }
            }
        }

        // epilogue: normalize by 1/l and store
        float rin[4];
        #pragma unroll
        for (int r = 0; r < 4; ++r) rin[r] = 1.0f / l[r];
        float* op = out + ((size_t)b * T_ + mt * 16) * H_;
        #pragma unroll
        for (int n = 0; n < 4; ++n)
            #pragma unroll
            for (int r = 0; r < 4; ++r)
                op[(lg * 4 + r) * H_ + n * 16 + lr] = oacc[n][r] * rin[r];
    }
}

extern "C" void kernel_launch(void* const* d_in, const int* in_sizes, int n_in,
                              void* d_out, int out_size, void* d_ws, size_t ws_size,
                              hipStream_t stream)
{
    (void)in_sizes; (void)n_in; (void)out_size;
    const float* x  = (const float*)d_in[0];
    const float* Wq = (const float*)d_in[1];
    const float* Wk = (const float*)d_in[2];
    const float* Wv = (const float*)d_in[3];
    float* o = (float*)d_out;

    if (ws_size >= (size_t)(3 * WT_STRIDE * sizeof(bf16))) {
        bf16* wt = (bf16*)d_ws;
        prep_wt<<<dim3((3 * WT_STRIDE + 255) / 256), dim3(256), 0, stream>>>(Wq, Wk, Wv, wt);
        head_fused3<1><<<dim3(B_), dim3(512), 0, stream>>>(x, Wq, Wk, Wv, wt, o);
    } else {
        head_fused3<0><<<dim3(B_), dim3(512), 0, stream>>>(x, Wq, Wk, Wv, nullptr, o);
    }
}

// Round 4
// 176.722 us; speedup vs baseline: 2.1223x; 1.2230x over previous
//
#include <hip/hip_runtime.h>

// Problem constants (fixed by the reference)
#define B_ 512
#define T_ 256
#define C_ 384
#define H_ 64
#define WT_STRIDE (H_ * C_)   // 24576 elements per matrix in WT scratch

typedef __bf16 bf16;
typedef bf16  bf16x8 __attribute__((ext_vector_type(8)));
typedef float f32x4  __attribute__((ext_vector_type(4)));

// ---------------- prep: W (fp32 [C][H]) -> WT (bf16 [mat][h][k]) ----------------
__global__ void prep_wt(const float* __restrict__ Wq,
                        const float* __restrict__ Wk,
                        const float* __restrict__ Wv,
                        bf16* __restrict__ wt)
{
    int idx = blockIdx.x * 256 + threadIdx.x;
    if (idx >= 3 * WT_STRIDE) return;
    int mat = idx / WT_STRIDE;
    int r   = idx % WT_STRIDE;
    int h   = r / C_;
    int k   = r % C_;
    const float* W = (mat == 0) ? Wq : (mat == 1) ? Wk : Wv;
    wt[idx] = (bf16)W[k * H_ + h];
}

__device__ __forceinline__ bf16x8 cvt8(float4 a, float4 b)
{
    bf16x8 r;
    r[0] = (bf16)a.x; r[1] = (bf16)a.y; r[2] = (bf16)a.z; r[3] = (bf16)a.w;
    r[4] = (bf16)b.x; r[5] = (bf16)b.y; r[6] = (bf16)b.z; r[7] = (bf16)b.w;
    return r;
}

template<int USE_WT>
__device__ __forceinline__ bf16x8 load_bfrag(const bf16* __restrict__ wt,
                                             const float* __restrict__ W,
                                             int mat, int col, int k)
{
    if (USE_WT) {
        return *reinterpret_cast<const bf16x8*>(wt + mat * WT_STRIDE + col * C_ + k);
    } else {
        bf16x8 r;
        const float* wp = W + k * H_ + col;
        #pragma unroll
        for (int j = 0; j < 8; ++j) r[j] = (bf16)wp[j * H_];
        return r;
    }
}

// XOR swizzle: permute 8-elem (16B) chunks within a row by low row bits.
#define SWZ(row, col) ((col) ^ (((row) & 7) << 3))

template<int USE_WT>
__global__ __launch_bounds__(512, 2)   // 2nd arg = min BLOCKS/CU (observed: R2 cap64, R3 cap128) -> VGPR cap 128
void head_fused4(const float* __restrict__ x,
                 const float* __restrict__ Wq,
                 const float* __restrict__ Wk,
                 const float* __restrict__ Wv,
                 const bf16* __restrict__ wt,
                 float* __restrict__ out)
{
    // 32768 + 32768 + 16384 = 81920 B -> exactly 2 blocks / 160 KiB CU
    __shared__ bf16 k_s[T_ * 64];       // [t=256][h=64]  swizzled
    __shared__ bf16 vT_s[H_ * 256];     // [h=64][t=256]  swizzled
    __shared__ bf16 p_s[8 * 16 * 64];   // per-wave bounce (q then P), swizzled

    const int tid  = threadIdx.x;
    const int wave = tid >> 6;
    const int lane = tid & 63;
    const int lr   = lane & 15;
    const int lg   = lane >> 4;

    const int b = blockIdx.x;
    const float* xb = x + (size_t)b * T_ * C_;
    bf16* pw = &p_s[wave * 16 * 64];

    bf16x8 qf[2][2];   // q A-fragments for this wave's two q-tiles (kept in regs)

    // ---------------- Phase 1: q,k,v projections (x read ONCE) ----------------
    // wave w owns row tiles {w, 15-w}; q stays in regs, k/vT go to LDS.
    #pragma unroll
    for (int p = 0; p < 2; ++p) {
        const int mt = p ? (15 - wave) : wave;
        f32x4 acc[3][4];   // q, k, v
        #pragma unroll
        for (int a = 0; a < 3; ++a)
            #pragma unroll
            for (int nw = 0; nw < 4; ++nw)
                acc[a][nw] = (f32x4){0.f, 0.f, 0.f, 0.f};

        const float* xrow = xb + (mt * 16 + lr) * C_;
        // unroll 2 (not full): caps the global-load hoist window so we stay
        // under the 128-VGPR budget instead of spilling ~100MB to scratch (R3).
        #pragma unroll 2
        for (int ks = 0; ks < 12; ++ks) {
            const float* xp = xrow + ks * 32 + lg * 8;
            float4 a0 = *reinterpret_cast<const float4*>(xp);
            float4 a1 = *reinterpret_cast<const float4*>(xp + 4);
            bf16x8 af = cvt8(a0, a1);
            #pragma unroll
            for (int nw = 0; nw < 4; ++nw) {
                bf16x8 bq = load_bfrag<USE_WT>(wt, Wq, 0, nw * 16 + lr, ks * 32 + lg * 8);
                acc[0][nw] = __builtin_amdgcn_mfma_f32_16x16x32_bf16(af, bq, acc[0][nw], 0, 0, 0);
                bf16x8 bk = load_bfrag<USE_WT>(wt, Wk, 1, nw * 16 + lr, ks * 32 + lg * 8);
                acc[1][nw] = __builtin_amdgcn_mfma_f32_16x16x32_bf16(af, bk, acc[1][nw], 0, 0, 0);
                bf16x8 bv = load_bfrag<USE_WT>(wt, Wv, 2, nw * 16 + lr, ks * 32 + lg * 8);
                acc[2][nw] = __builtin_amdgcn_mfma_f32_16x16x32_bf16(af, bv, acc[2][nw], 0, 0, 0);
            }
        }
        // D layout: row = lg*4+r (within tile), col = lr (within n-block)
        #pragma unroll
        for (int nw = 0; nw < 4; ++nw) {
            #pragma unroll
            for (int r = 0; r < 4; ++r) {
                int row = mt * 16 + lg * 4 + r;   // t
                int col = nw * 16 + lr;           // h
                k_s[row * 64 + SWZ(row, col)]   = (bf16)acc[1][nw][r];
                vT_s[col * 256 + SWZ(col, row)] = (bf16)acc[2][nw][r];
            }
        }
        // q: D-layout -> A-fragment layout via per-wave bounce, keep in regs
        #pragma unroll
        for (int nw = 0; nw < 4; ++nw) {
            #pragma unroll
            for (int r = 0; r < 4; ++r) {
                int row = lg * 4 + r;
                pw[row * 64 + SWZ(row, nw * 16 + lr)] = (bf16)acc[0][nw][r];
            }
        }
        asm volatile("s_waitcnt lgkmcnt(0)" ::: "memory");
        __builtin_amdgcn_sched_barrier(0);
        qf[p][0] = *reinterpret_cast<const bf16x8*>(&pw[lr * 64 + SWZ(lr, lg * 8)]);
        qf[p][1] = *reinterpret_cast<const bf16x8*>(&pw[lr * 64 + SWZ(lr, 32 + lg * 8)]);
        __builtin_amdgcn_sched_barrier(0);   // fence p-bodies apart (pressure)
    }
    __syncthreads();   // k_s / vT_s complete

    // ---------------- Phase 2: causal attention, flash-style two halves ----------------
    const float scale = 0.051031036307982884f;   // 384^-0.5 (C, not H)

    #pragma unroll
    for (int p = 0; p < 2; ++p) {
        const int mt  = p ? (15 - wave) : wave;
        const int nkt = mt + 1;                   // valid key tiles

        float m[4], l[4];
        f32x4 oacc[4];
        #pragma unroll
        for (int r = 0; r < 4; ++r) { m[r] = -1e30f; l[r] = 0.f; }
        #pragma unroll
        for (int n = 0; n < 4; ++n) oacc[n] = (f32x4){0.f, 0.f, 0.f, 0.f};

        #pragma unroll
        for (int h = 0; h < 2; ++h) {
            const int vh = (nkt - h * 8) < 8 ? (nkt - h * 8) : 8;   // valid tiles in half
            if (vh > 0) {   // wave-uniform
                float s[8][4];
                #pragma unroll
                for (int j = 0; j < 8; ++j) {
                    const int kt = h * 8 + j;
                    if (j < vh) {   // wave-uniform
                        bf16x8 kf0 = *reinterpret_cast<const bf16x8*>(
                            &k_s[(kt * 16 + lr) * 64 + SWZ(lr, lg * 8)]);
                        bf16x8 kf1 = *reinterpret_cast<const bf16x8*>(
                            &k_s[(kt * 16 + lr) * 64 + SWZ(lr, 32 + lg * 8)]);
                        f32x4 sc = (f32x4){0.f, 0.f, 0.f, 0.f};
                        sc = __builtin_amdgcn_mfma_f32_16x16x32_bf16(qf[p][0], kf0, sc, 0, 0, 0);
                        sc = __builtin_amdgcn_mfma_f32_16x16x32_bf16(qf[p][1], kf1, sc, 0, 0, 0);
                        #pragma unroll
                        for (int r = 0; r < 4; ++r) {
                            float v = sc[r] * scale;
                            if (kt == mt && lr > lg * 4 + r) v = -1e30f;   // causal diag
                            s[j][r] = v;
                        }
                    } else {
                        #pragma unroll
                        for (int r = 0; r < 4; ++r) s[j][r] = -1e30f;
                    }
                    // pin in pairs: limits k-frag hoisting (reg pressure),
                    // keeps s[] static indexing (full source unroll preserved)
                    if ((j & 1) == 1) __builtin_amdgcn_sched_barrier(0);
                }

                // per-row max of this half (row lg*4+r spans the 16 lanes of the group)
                float f[4];
                #pragma unroll
                for (int r = 0; r < 4; ++r) {
                    float pm = s[0][r];
                    #pragma unroll
                    for (int j = 1; j < 8; ++j) pm = fmaxf(pm, s[j][r]);
                    pm = fmaxf(pm, __shfl_xor(pm, 1));
                    pm = fmaxf(pm, __shfl_xor(pm, 2));
                    pm = fmaxf(pm, __shfl_xor(pm, 4));
                    pm = fmaxf(pm, __shfl_xor(pm, 8));
                    float nm = fmaxf(m[r], pm);
                    f[r] = __expf(m[r] - nm);   // rescale factor (0 on first half)
                    m[r] = nm;
                    l[r] *= f[r];
                }
                #pragma unroll
                for (int n = 0; n < 4; ++n)
                    #pragma unroll
                    for (int r = 0; r < 4; ++r)
                        oacc[n][r] *= f[r];

                // exp + row sum
                #pragma unroll
                for (int r = 0; r < 4; ++r) {
                    float t = 0.f;
                    #pragma unroll
                    for (int j = 0; j < 8; ++j) {
                        float e = __expf(s[j][r] - m[r]);
                        s[j][r] = e;
                        t += e;
                    }
                    t += __shfl_xor(t, 1);
                    t += __shfl_xor(t, 2);
                    t += __shfl_xor(t, 4);
                    t += __shfl_xor(t, 8);
                    l[r] += t;
                }

                // PV (unnormalized P through the bounce)
                const int nkk = (vh + 1) >> 1;
                #pragma unroll
                for (int kkl = 0; kkl < 4; ++kkl) {
                    if (kkl < nkk) {   // wave-uniform
                        const int kk = h * 4 + kkl;
                        #pragma unroll
                        for (int r = 0; r < 4; ++r) {
                            int row = lg * 4 + r;
                            pw[row * 64 + SWZ(row, lr)]      = (bf16)s[2 * kkl][r];
                            pw[row * 64 + SWZ(row, 16 + lr)] = (bf16)s[2 * kkl + 1][r];
                        }
                        asm volatile("s_waitcnt lgkmcnt(0)" ::: "memory");
                        __builtin_amdgcn_sched_barrier(0);
                        bf16x8 pf = *reinterpret_cast<const bf16x8*>(
                            &pw[lr * 64 + SWZ(lr, lg * 8)]);
                        #pragma unroll
                        for (int n = 0; n < 4; ++n) {
                            bf16x8 vf = *reinterpret_cast<const bf16x8*>(
                                &vT_s[(n * 16 + lr) * 256 + SWZ(lr, kk * 32 + lg * 8)]);
                            oacc[n] = __builtin_amdgcn_mfma_f32_16x16x32_bf16(pf, vf, oacc[n], 0, 0, 0);
                        }
                    }
                }
            }
        }

        // epilogue: normalize by 1/l and store
        float rin[4];
        #pragma unroll
        for (int r = 0; r < 4; ++r) rin[r] = 1.0f / l[r];
        float* op = out + ((size_t)b * T_ + mt * 16) * H_;
        #pragma unroll
        for (int n = 0; n < 4; ++n)
            #pragma unroll
            for (int r = 0; r < 4; ++r)
                op[(lg * 4 + r) * H_ + n * 16 + lr] = oacc[n][r] * rin[r];
    }
}

extern "C" void kernel_launch(void* const* d_in, const int* in_sizes, int n_in,
                              void* d_out, int out_size, void* d_ws, size_t ws_size,
                              hipStream_t stream)
{
    (void)in_sizes; (void)n_in; (void)out_size;
    const float* x  = (const float*)d_in[0];
    const float* Wq = (const float*)d_in[1];
    const float* Wk = (const float*)d_in[2];
    const float* Wv = (const float*)d_in[3];
    float* o = (float*)d_out;

    if (ws_size >= (size_t)(3 * WT_STRIDE * sizeof(bf16))) {
        bf16* wt = (bf16*)d_ws;
        prep_wt<<<dim3((3 * WT_STRIDE + 255) / 256), dim3(256), 0, stream>>>(Wq, Wk, Wv, wt);
        head_fused4<1><<<dim3(B_), dim3(512), 0, stream>>>(x, Wq, Wk, Wv, wt, o);
    } else {
        head_fused4<0><<<dim3(B_), dim3(512), 0, stream>>>(x, Wq, Wk, Wv, nullptr, o);
    }
}

// Round 5
// 76.993 us; speedup vs baseline: 4.8713x; 2.2953x over previous
//
#include <hip/hip_runtime.h>

// Problem constants (fixed by the reference)
#define B_ 512
#define T_ 256
#define C_ 384
#define H_ 64
#define WT_STRIDE (H_ * C_)   // 24576 elements per matrix in WT scratch

typedef __bf16 bf16;
typedef bf16  bf16x8 __attribute__((ext_vector_type(8)));
typedef float f32x4  __attribute__((ext_vector_type(4)));

// ---------------- prep: W (fp32 [C][H]) -> WT (bf16 [mat][h][k]) ----------------
__global__ void prep_wt(const float* __restrict__ Wq,
                        const float* __restrict__ Wk,
                        const float* __restrict__ Wv,
                        bf16* __restrict__ wt)
{
    int idx = blockIdx.x * 256 + threadIdx.x;
    if (idx >= 3 * WT_STRIDE) return;
    int mat = idx / WT_STRIDE;
    int r   = idx % WT_STRIDE;
    int h   = r / C_;
    int k   = r % C_;
    const float* W = (mat == 0) ? Wq : (mat == 1) ? Wk : Wv;
    wt[idx] = (bf16)W[k * H_ + h];
}

__device__ __forceinline__ bf16x8 cvt8(float4 a, float4 b)
{
    bf16x8 r;
    r[0] = (bf16)a.x; r[1] = (bf16)a.y; r[2] = (bf16)a.z; r[3] = (bf16)a.w;
    r[4] = (bf16)b.x; r[5] = (bf16)b.y; r[6] = (bf16)b.z; r[7] = (bf16)b.w;
    return r;
}

// XOR swizzle for k_s / vT_s / p_s: permute 8-elem (16B) chunks within a row.
#define SWZ(row, col) ((col) ^ (((row) & 7) << 3))

// wt_s fragment address: [mc = mat*64+col][kk 0..191] bf16, byte-swizzled.
// bank check: 16 lanes (col=nw*16+lr) -> banks 4*(lg^(col&7)) -> 2-way max (free).
__device__ __forceinline__ const bf16x8* wts_frag(const bf16* wt_s, int mc, int kk)
{
    int byte = ((mc * 192 + kk) * 2) ^ ((mc & 7) << 4);
    return reinterpret_cast<const bf16x8*>(reinterpret_cast<const char*>(wt_s) + byte);
}

template<int USE_WT>
__global__ __launch_bounds__(512, 1)   // 1 block/CU (LDS 152KB) -> 2 waves/SIMD -> VGPR cap 256
void head_fused5(const float* __restrict__ x,
                 const float* __restrict__ Wq,
                 const float* __restrict__ Wk,
                 const float* __restrict__ Wv,
                 const bf16* __restrict__ wt,
                 float* __restrict__ out)
{
    // 73728 + 32768 + 32768 + 16384 = 155648 B <= 160 KiB (1 block/CU)
    __shared__ bf16 wt_s[3 * 64 * 192];  // [mat*64+col][kk] half-K of all 3 mats
    __shared__ bf16 k_s[T_ * 64];        // [t=256][h=64]  swizzled
    __shared__ bf16 vT_s[H_ * 256];      // [h=64][t=256]  swizzled
    __shared__ bf16 p_s[8 * 16 * 64];    // per-wave bounce (q then P), swizzled

    const int tid  = threadIdx.x;
    const int wave = tid >> 6;
    const int lane = tid & 63;
    const int lr   = lane & 15;
    const int lg   = lane >> 4;

    const int b = blockIdx.x;
    const float* xb = x + (size_t)b * T_ * C_;
    bf16* pw = &p_s[wave * 16 * 64];

    bf16x8 qf[2][2];   // q A-fragments for this wave's two q-tiles

    // ---------------- Phase 1: q,k,v projections ----------------
    // wave w owns row tiles {w, 15-w}. K split in halves; wt_s restaged per
    // (p, half) — 4 stages, tiny traffic (147KB L2-hot). x read ONCE per elem.
    #pragma unroll
    for (int p = 0; p < 2; ++p) {
        const int mt = p ? (15 - wave) : wave;
        f32x4 acc[3][4];   // q, k, v  (live across both K-halves)
        #pragma unroll
        for (int a = 0; a < 3; ++a)
            #pragma unroll
            for (int nw = 0; nw < 4; ++nw)
                acc[a][nw] = (f32x4){0.f, 0.f, 0.f, 0.f};

        #pragma unroll
        for (int half = 0; half < 2; ++half) {
            __syncthreads();   // previous wt_s consumers done
            // ---- stage wt_s: 4608 16B chunks over 512 threads = 9 each ----
            if (USE_WT) {
                bf16x8 v[9];
                #pragma unroll
                for (int c = 0; c < 9; ++c) {   // batched: 9 loads in flight
                    int f16 = c * 512 + tid;    // chunk idx; f16 = mc*24 + kkc
                    int mc  = f16 / 24;
                    int kkc = f16 % 24;
                    v[c] = *reinterpret_cast<const bf16x8*>(
                        wt + mc * 384 + half * 192 + kkc * 8);
                }
                #pragma unroll
                for (int c = 0; c < 9; ++c) {
                    int f16 = c * 512 + tid;
                    int mc  = f16 / 24;
                    int kkc = f16 % 24;
                    int byte = ((mc * 192 + kkc * 8) * 2) ^ ((mc & 7) << 4);
                    *reinterpret_cast<bf16x8*>(
                        reinterpret_cast<char*>(wt_s) + byte) = v[c];
                }
            } else {
                // fallback: gather from fp32 W (strided) — correct, slower
                #pragma unroll
                for (int c = 0; c < 9; ++c) {
                    int f16 = c * 512 + tid;
                    int mc  = f16 / 24;
                    int kkc = f16 % 24;
                    int mat = mc >> 6, col = mc & 63;
                    const float* W = (mat == 0) ? Wq : (mat == 1) ? Wk : Wv;
                    bf16x8 vv;
                    #pragma unroll
                    for (int j = 0; j < 8; ++j)
                        vv[j] = (bf16)W[(half * 192 + kkc * 8 + j) * H_ + col];
                    int byte = ((mc * 192 + kkc * 8) * 2) ^ ((mc & 7) << 4);
                    *reinterpret_cast<bf16x8*>(
                        reinterpret_cast<char*>(wt_s) + byte) = vv;
                }
            }
            __syncthreads();   // wt_s ready

            // ---- x: all 12 float4 for this (tile, half) issued up front ----
            const float* xrow = xb + (mt * 16 + lr) * C_ + half * 192 + lg * 8;
            float4 xa[6][2];
            #pragma unroll
            for (int ks = 0; ks < 6; ++ks) {
                xa[ks][0] = *reinterpret_cast<const float4*>(xrow + ks * 32);
                xa[ks][1] = *reinterpret_cast<const float4*>(xrow + ks * 32 + 4);
            }
            // ---- consume: MFMA against LDS-resident WT ----
            #pragma unroll
            for (int ks = 0; ks < 6; ++ks) {
                bf16x8 af = cvt8(xa[ks][0], xa[ks][1]);
                const int kk = ks * 32 + lg * 8;
                #pragma unroll
                for (int nw = 0; nw < 4; ++nw) {
                    const int col = nw * 16 + lr;
                    acc[0][nw] = __builtin_amdgcn_mfma_f32_16x16x32_bf16(
                        af, *wts_frag(wt_s, col, kk), acc[0][nw], 0, 0, 0);
                    acc[1][nw] = __builtin_amdgcn_mfma_f32_16x16x32_bf16(
                        af, *wts_frag(wt_s, 64 + col, kk), acc[1][nw], 0, 0, 0);
                    acc[2][nw] = __builtin_amdgcn_mfma_f32_16x16x32_bf16(
                        af, *wts_frag(wt_s, 128 + col, kk), acc[2][nw], 0, 0, 0);
                }
            }
        }

        // D layout: row = lg*4+r (within tile), col = lr (within n-block)
        #pragma unroll
        for (int nw = 0; nw < 4; ++nw) {
            #pragma unroll
            for (int r = 0; r < 4; ++r) {
                int row = mt * 16 + lg * 4 + r;   // t
                int col = nw * 16 + lr;           // h
                k_s[row * 64 + SWZ(row, col)]   = (bf16)acc[1][nw][r];
                vT_s[col * 256 + SWZ(col, row)] = (bf16)acc[2][nw][r];
            }
        }
        // q: D-layout -> A-fragment layout via per-wave bounce, keep in regs
        #pragma unroll
        for (int nw = 0; nw < 4; ++nw) {
            #pragma unroll
            for (int r = 0; r < 4; ++r) {
                int row = lg * 4 + r;
                pw[row * 64 + SWZ(row, nw * 16 + lr)] = (bf16)acc[0][nw][r];
            }
        }
        asm volatile("s_waitcnt lgkmcnt(0)" ::: "memory");
        __builtin_amdgcn_sched_barrier(0);
        qf[p][0] = *reinterpret_cast<const bf16x8*>(&pw[lr * 64 + SWZ(lr, lg * 8)]);
        qf[p][1] = *reinterpret_cast<const bf16x8*>(&pw[lr * 64 + SWZ(lr, 32 + lg * 8)]);
    }
    __syncthreads();   // k_s / vT_s complete

    // ---------------- Phase 2: causal attention, flash-style two halves ----------------
    const float scale = 0.051031036307982884f;   // 384^-0.5 (C, not H)

    #pragma unroll
    for (int p = 0; p < 2; ++p) {
        const int mt  = p ? (15 - wave) : wave;
        const int nkt = mt + 1;                   // valid key tiles

        float m[4], l[4];
        f32x4 oacc[4];
        #pragma unroll
        for (int r = 0; r < 4; ++r) { m[r] = -1e30f; l[r] = 0.f; }
        #pragma unroll
        for (int n = 0; n < 4; ++n) oacc[n] = (f32x4){0.f, 0.f, 0.f, 0.f};

        #pragma unroll
        for (int h = 0; h < 2; ++h) {
            const int vh = (nkt - h * 8) < 8 ? (nkt - h * 8) : 8;   // valid tiles in half
            if (vh > 0) {   // wave-uniform
                float s[8][4];
                #pragma unroll
                for (int j = 0; j < 8; ++j) {
                    const int kt = h * 8 + j;
                    if (j < vh) {   // wave-uniform; no sched pins — let loads hoist
                        bf16x8 kf0 = *reinterpret_cast<const bf16x8*>(
                            &k_s[(kt * 16 + lr) * 64 + SWZ(lr, lg * 8)]);
                        bf16x8 kf1 = *reinterpret_cast<const bf16x8*>(
                            &k_s[(kt * 16 + lr) * 64 + SWZ(lr, 32 + lg * 8)]);
                        f32x4 sc = (f32x4){0.f, 0.f, 0.f, 0.f};
                        sc = __builtin_amdgcn_mfma_f32_16x16x32_bf16(qf[p][0], kf0, sc, 0, 0, 0);
                        sc = __builtin_amdgcn_mfma_f32_16x16x32_bf16(qf[p][1], kf1, sc, 0, 0, 0);
                        #pragma unroll
                        for (int r = 0; r < 4; ++r) {
                            float v = sc[r] * scale;
                            if (kt == mt && lr > lg * 4 + r) v = -1e30f;   // causal diag
                            s[j][r] = v;
                        }
                    } else {
                        #pragma unroll
                        for (int r = 0; r < 4; ++r) s[j][r] = -1e30f;
                    }
                }

                // per-row max of this half (row lg*4+r spans the 16 lanes of the group)
                float f[4];
                #pragma unroll
                for (int r = 0; r < 4; ++r) {
                    float pm = s[0][r];
                    #pragma unroll
                    for (int j = 1; j < 8; ++j) pm = fmaxf(pm, s[j][r]);
                    pm = fmaxf(pm, __shfl_xor(pm, 1));
                    pm = fmaxf(pm, __shfl_xor(pm, 2));
                    pm = fmaxf(pm, __shfl_xor(pm, 4));
                    pm = fmaxf(pm, __shfl_xor(pm, 8));
                    float nm = fmaxf(m[r], pm);
                    f[r] = __expf(m[r] - nm);   // rescale factor (0 on first half)
                    m[r] = nm;
                    l[r] *= f[r];
                }
                #pragma unroll
                for (int n = 0; n < 4; ++n)
                    #pragma unroll
                    for (int r = 0; r < 4; ++r)
                        oacc[n][r] *= f[r];

                // exp + row sum
                #pragma unroll
                for (int r = 0; r < 4; ++r) {
                    float t = 0.f;
                    #pragma unroll
                    for (int j = 0; j < 8; ++j) {
                        float e = __expf(s[j][r] - m[r]);
                        s[j][r] = e;
                        t += e;
                    }
                    t += __shfl_xor(t, 1);
                    t += __shfl_xor(t, 2);
                    t += __shfl_xor(t, 4);
                    t += __shfl_xor(t, 8);
                    l[r] += t;
                }

                // PV (unnormalized P through the bounce)
                const int nkk = (vh + 1) >> 1;
                #pragma unroll
                for (int kkl = 0; kkl < 4; ++kkl) {
                    if (kkl < nkk) {   // wave-uniform
                        const int kk = h * 4 + kkl;
                        #pragma unroll
                        for (int r = 0; r < 4; ++r) {
                            int row = lg * 4 + r;
                            pw[row * 64 + SWZ(row, lr)]      = (bf16)s[2 * kkl][r];
                            pw[row * 64 + SWZ(row, 16 + lr)] = (bf16)s[2 * kkl + 1][r];
                        }
                        asm volatile("s_waitcnt lgkmcnt(0)" ::: "memory");
                        __builtin_amdgcn_sched_barrier(0);
                        bf16x8 pf = *reinterpret_cast<const bf16x8*>(
                            &pw[lr * 64 + SWZ(lr, lg * 8)]);
                        #pragma unroll
                        for (int n = 0; n < 4; ++n) {
                            bf16x8 vf = *reinterpret_cast<const bf16x8*>(
                                &vT_s[(n * 16 + lr) * 256 + SWZ(lr, kk * 32 + lg * 8)]);
                            oacc[n] = __builtin_amdgcn_mfma_f32_16x16x32_bf16(pf, vf, oacc[n], 0, 0, 0);
                        }
                    }
                }
            }
        }

        // epilogue: normalize by 1/l and store
        float rin[4];
        #pragma unroll
        for (int r = 0; r < 4; ++r) rin[r] = 1.0f / l[r];
        float* op = out + ((size_t)b * T_ + mt * 16) * H_;
        #pragma unroll
        for (int n = 0; n < 4; ++n)
            #pragma unroll
            for (int r = 0; r < 4; ++r)
                op[(lg * 4 + r) * H_ + n * 16 + lr] = oacc[n][r] * rin[r];
    }
}

extern "C" void kernel_launch(void* const* d_in, const int* in_sizes, int n_in,
                              void* d_out, int out_size, void* d_ws, size_t ws_size,
                              hipStream_t stream)
{
    (void)in_sizes; (void)n_in; (void)out_size;
    const float* x  = (const float*)d_in[0];
    const float* Wq = (const float*)d_in[1];
    const float* Wk = (const float*)d_in[2];
    const float* Wv = (const float*)d_in[3];
    float* o = (float*)d_out;

    if (ws_size >= (size_t)(3 * WT_STRIDE * sizeof(bf16))) {
        bf16* wt = (bf16*)d_ws;
        prep_wt<<<dim3((3 * WT_STRIDE + 255) / 256), dim3(256), 0, stream>>>(Wq, Wk, Wv, wt);
        head_fused5<1><<<dim3(B_), dim3(512), 0, stream>>>(x, Wq, Wk, Wv, wt, o);
    } else {
        head_fused5<0><<<dim3(B_), dim3(512), 0, stream>>>(x, Wq, Wk, Wv, nullptr, o);
    }
}